// Round 8
// baseline (131.001 us; speedup 1.0000x reference)
//
#include <hip/hip_runtime.h>
#include <hip/hip_bf16.h>

#define DEVI __device__ __forceinline__

typedef float f32x4 __attribute__((ext_vector_type(4)));
typedef _Float16 f16x8 __attribute__((ext_vector_type(8)));
typedef short s16x8 __attribute__((ext_vector_type(8)));

constexpr int NB = 8;     // batch
constexpr int HW = 1024;  // i (query) dim
constexpr int KD = 128;   // QK reduction dim
constexpr int VD = 512;   // value dim
constexpr int NJ = 2048;  // j (key/col) dim

// Fragment-major layouts: [..tile..][..k-chunk..][lane 64][elem 8]
// QB f16  [2 src][8 b][64 it][4 kc][512]
// KT f16  [2 src][8 b][128 jt][4 kc][512]
// MV bf16 [8 b][32 vt][64 jc][512]
// P  bf16 [8 b][64 it][64 jc][512]          (ws_size = 256 MiB, plenty)
constexpr size_t WS_KT = 0;                                    // 8.39 MB
constexpr size_t WS_QB = WS_KT + (size_t)2*NB*NJ*KD*2;         // 4.19 MB
constexpr size_t WS_MV = WS_QB + (size_t)2*NB*HW*KD*2;         // 16.78 MB
constexpr size_t WS_D  = WS_MV + (size_t)NB*VD*NJ*2;           // 2.10 MB
constexpr size_t WS_P  = WS_D  + (size_t)4*4*NB*NJ*4;          // 33.55 MB
constexpr size_t WS_NEED = WS_P + (size_t)NB*HW*NJ*2;          // ~65 MB total
constexpr size_t PBF = (size_t)64*64*512;                      // P shorts per batch

DEVI unsigned short f2bf(float x) {
    unsigned int u = __builtin_bit_cast(unsigned int, x);
    u += 0x7fffu + ((u >> 16) & 1u);
    return (unsigned short)(u >> 16);
}

// ---------------- k_prep: kt-transpose blocks + flat cvt/copy blocks ----------------
// blocks [0,512): K [d][j] fp32 -> f16 B-frags (LDS transpose tile)
// blocks [512,2560): grid-stride { q cvt -> QB frags, m_val cvt -> MV frags, q_val copy }
__global__ __launch_bounds__(256) void k_prep(
    const float* __restrict__ k0, const float* __restrict__ k1,
    const float* __restrict__ q0, const float* __restrict__ q1,
    const float* __restrict__ mv, const float* __restrict__ qv,
    unsigned short* __restrict__ KT, unsigned short* __restrict__ QB,
    unsigned short* __restrict__ MV, float* __restrict__ out) {
    __shared__ _Float16 Lt[64][136];
    int bid = blockIdx.x;
    int t = threadIdx.x;
    if (bid < 512) {
        int jt64 = bid & 31, b = (bid >> 5) & 7, src = bid >> 8;
        const float* K = (src ? k1 : k0) + (size_t)b * KD * NJ;
#pragma unroll
        for (int rd = 0; rd < 8; ++rd) {
            int task = t + rd * 256;
            int d = task >> 4, j4 = (task & 15) * 4;
            float4 v = *(const float4*)&K[(size_t)d * NJ + jt64 * 64 + j4];
            Lt[j4 + 0][d] = (_Float16)v.x;
            Lt[j4 + 1][d] = (_Float16)v.y;
            Lt[j4 + 2][d] = (_Float16)v.z;
            Lt[j4 + 3][d] = (_Float16)v.w;
        }
        __syncthreads();
        int w = t >> 6, l = t & 63, lr = l & 15, lg = l >> 4;
        int jt = jt64 * 4 + w;
#pragma unroll
        for (int kc = 0; kc < 4; ++kc) {
            f16x8 v = *(const f16x8*)&Lt[w * 16 + lr][kc * 32 + lg * 8];
            *(f16x8*)&KT[((((size_t)src * NB + b) * 128 + jt) * 4 + kc) * 512 + l * 8] = v;
        }
        return;
    }
    const int NTQ = 2 * NB * 64 * 4 * 64;        // 262144
    const int NTV = NB * 32 * 64 * 64;           // 1048576
    const int NQV = NB * VD * HW / 4;            // 1048576 float4 copies
    const int total = NTQ + NTV + NQV;
    const int stride = 2048 * 256;
    for (int task = (bid - 512) * 256 + t; task < total; task += stride) {
        if (task < NTQ) {
            int l = task & 63, kc = (task >> 6) & 3, it = (task >> 8) & 63;
            int b = (task >> 14) & 7, src = task >> 17;
            int lr = l & 15, lg = l >> 4;
            const float* q = (src ? q1 : q0) + (size_t)b * HW * KD
                           + (size_t)(it * 16 + lr) * KD + kc * 32 + lg * 8;
            float4 x0 = *(const float4*)q, x1 = *(const float4*)(q + 4);
            f16x8 r;
            r[0]=(_Float16)x0.x; r[1]=(_Float16)x0.y; r[2]=(_Float16)x0.z; r[3]=(_Float16)x0.w;
            r[4]=(_Float16)x1.x; r[5]=(_Float16)x1.y; r[6]=(_Float16)x1.z; r[7]=(_Float16)x1.w;
            *(f16x8*)&QB[((((size_t)src * NB + b) * 64 + it) * 4 + kc) * 512 + l * 8] = r;
        } else if (task < NTQ + NTV) {
            int t2 = task - NTQ;
            int l = t2 & 63, jc = (t2 >> 6) & 63, vt = (t2 >> 12) & 31, b = t2 >> 17;
            int lr = l & 15, lg = l >> 4;
            const float* p = mv + (size_t)b * VD * NJ + (size_t)(vt * 16 + lr) * NJ + jc * 32 + lg * 8;
            float4 x0 = *(const float4*)p, x1 = *(const float4*)(p + 4);
            s16x8 r;
            r[0]=(short)f2bf(x0.x); r[1]=(short)f2bf(x0.y); r[2]=(short)f2bf(x0.z); r[3]=(short)f2bf(x0.w);
            r[4]=(short)f2bf(x1.x); r[5]=(short)f2bf(x1.y); r[6]=(short)f2bf(x1.z); r[7]=(short)f2bf(x1.w);
            *(s16x8*)&MV[(((size_t)b * 32 + vt) * 64 + jc) * 512 + l * 8] = r;
        } else {
            int t3 = task - NTQ - NTV;
            int b = t3 >> 17, t4 = t3 & 131071;
            float4 v = ((const float4*)qv)[t3];
            ((float4*)(out + (size_t)b * 1048576 + 524288))[t4] = v;
        }
    }
}

// ---------------- k_stats: column sumexp; <=128 VGPR, 4 blocks/CU ----------------
// grid 1024: b=bid&7; r=bid>>3: jb=r&15, is=(r>>4)&3, kc=r>>6
__global__ __launch_bounds__(256, 4) void k_stats(
    const unsigned short* __restrict__ KTu, const unsigned short* __restrict__ QBu,
    float* __restrict__ d_part) {
    int bid = blockIdx.x;
    int b = bid & 7, r = bid >> 3;
    int jb = r & 15, is = (r >> 4) & 3, kc_s = r >> 6;
    int t = threadIdx.x, w = t >> 6, l = t & 63, lr = l & 15, lg = l >> 4;
    f16x8 bk[2][4];
#pragma unroll
    for (int tj = 0; tj < 2; ++tj) {
        int jt = jb * 8 + w * 2 + tj;
#pragma unroll
        for (int kst = 0; kst < 4; ++kst)
            bk[tj][kst] = *(const f16x8*)&KTu[((((size_t)kc_s * NB + b) * 128 + jt) * 4 + kst) * 512 + l * 8];
    }
    float dacc[2][2];
    dacc[0][0] = dacc[0][1] = dacc[1][0] = dacc[1][1] = 0.f;

#pragma unroll 2
    for (int it = 0; it < 16; ++it) {
        int itile = is * 16 + it;
#pragma unroll
        for (int qc = 0; qc < 2; ++qc) {
            f16x8 aq[4];
#pragma unroll
            for (int kst = 0; kst < 4; ++kst)
                aq[kst] = *(const f16x8*)&QBu[((((size_t)qc * NB + b) * 64 + itile) * 4 + kst) * 512 + l * 8];
#pragma unroll
            for (int tj = 0; tj < 2; ++tj) {
                f32x4 c = {0.f, 0.f, 0.f, 0.f};
#pragma unroll
                for (int kst = 0; kst < 4; ++kst)
                    c = __builtin_amdgcn_mfma_f32_16x16x32_f16(aq[kst], bk[tj][kst], c, 0, 0, 0);
#pragma unroll
                for (int rr = 0; rr < 4; ++rr) dacc[qc][tj] += __expf(c[rr]);
            }
        }
    }
#pragma unroll
    for (int qc = 0; qc < 2; ++qc)
#pragma unroll
        for (int tj = 0; tj < 2; ++tj) {
            float v = dacc[qc][tj];
            v += __shfl_xor(v, 16, 64);
            v += __shfl_xor(v, 32, 64);
            if (lg == 0) {
                int br = qc * 2 + kc_s;
                int j = (jb * 8 + w * 2 + tj) * 16 + lr;
                d_part[(((size_t)is * 4 + br) * NB + b) * NJ + j] = v;
            }
        }
}

// ---------------- k_pmat: P = sum_br exp(S_br)/d_br -> bf16 frags ----------------
// grid 1024: b=bid&7; r=bid>>3: jb=r&15, ib=r>>4 (128 i per block)
// holds+prefetches bk (one jc ahead); streams aq per (jc,qc) from L1
__global__ __launch_bounds__(256, 4) void k_pmat(
    const unsigned short* __restrict__ KTu, const unsigned short* __restrict__ QBu,
    const float* __restrict__ d_part, unsigned short* __restrict__ P0) {
    __shared__ unsigned short Ps[4][32][136];   // 34.8 KB wave-private strips
    __shared__ float ivd[4][128];
    int bid = blockIdx.x;
    int b = bid & 7, r = bid >> 3;
    int jb = r & 15, ib = r >> 4;
    int t = threadIdx.x, w = t >> 6, l = t & 63, lr = l & 15, lg = l >> 4;

    for (int e = t; e < 512; e += 256) {
        int br = e >> 7, jj = e & 127;
        size_t o = ((size_t)br * NB + b) * NJ + jb * 128 + jj;
        const size_t S = (size_t)4 * NB * NJ;
        ivd[br][jj] = 1.0f / (d_part[o] + d_part[o + S] + d_part[o + 2 * S] + d_part[o + 3 * S]);
    }
    __syncthreads();

    // current-jc bk (both kc), prefetched one jc ahead
    f16x8 bkA[2][4];
#pragma unroll
    for (int kc = 0; kc < 2; ++kc)
#pragma unroll
        for (int kst = 0; kst < 4; ++kst)
            bkA[kc][kst] = *(const f16x8*)&KTu[((((size_t)kc * NB + b) * 128 + jb * 8) * 4 + kst) * 512 + l * 8];

#pragma unroll 1
    for (int jc = 0; jc < 8; ++jc) {
        f16x8 bkB[2][4];
        if (jc < 7) {
            int jtn = jb * 8 + jc + 1;
#pragma unroll
            for (int kc = 0; kc < 2; ++kc)
#pragma unroll
                for (int kst = 0; kst < 4; ++kst)
                    bkB[kc][kst] = *(const f16x8*)&KTu[((((size_t)kc * NB + b) * 128 + jtn) * 4 + kst) * 512 + l * 8];
        } else {
#pragma unroll
            for (int kc = 0; kc < 2; ++kc)
#pragma unroll
                for (int kst = 0; kst < 4; ++kst) bkB[kc][kst] = bkA[kc][kst];
        }
        float iv[4];
#pragma unroll
        for (int br = 0; br < 4; ++br) iv[br] = ivd[br][jc * 16 + lr];
        f32x4 pacc[2] = {{0.f,0.f,0.f,0.f},{0.f,0.f,0.f,0.f}};
#pragma unroll
        for (int qc = 0; qc < 2; ++qc) {
            f16x8 aq[2][4];
#pragma unroll
            for (int ti = 0; ti < 2; ++ti)
#pragma unroll
                for (int kst = 0; kst < 4; ++kst)
                    aq[ti][kst] = *(const f16x8*)&QBu[((((size_t)qc * NB + b) * 64 + ib * 8 + w * 2 + ti) * 4 + kst) * 512 + l * 8];
#pragma unroll
            for (int kc = 0; kc < 2; ++kc) {
                float ivb = iv[qc * 2 + kc];
#pragma unroll
                for (int ti = 0; ti < 2; ++ti) {
                    f32x4 c = {0.f, 0.f, 0.f, 0.f};
#pragma unroll
                    for (int kst = 0; kst < 4; ++kst)
                        c = __builtin_amdgcn_mfma_f32_16x16x32_f16(aq[ti][kst], bkA[kc][kst], c, 0, 0, 0);
#pragma unroll
                    for (int rr = 0; rr < 4; ++rr)
                        pacc[ti][rr] += __expf(c[rr]) * ivb;
                }
            }
        }
#pragma unroll
        for (int ti = 0; ti < 2; ++ti)
#pragma unroll
            for (int rr = 0; rr < 4; ++rr)
                Ps[w][ti * 16 + lg * 4 + rr][jc * 16 + lr] = f2bf(pacc[ti][rr]);
#pragma unroll
        for (int kc = 0; kc < 2; ++kc)
#pragma unroll
            for (int kst = 0; kst < 4; ++kst) bkA[kc][kst] = bkB[kc][kst];
    }
    // wave-private epilogue: read back as A-fragments, store contiguous
    unsigned short* Pg = P0 + (size_t)b * PBF;
    int itl_base = ib * 8 + w * 2;
#pragma unroll
    for (int it2 = 0; it2 < 2; ++it2)
#pragma unroll
        for (int jcq = 0; jcq < 4; ++jcq) {
            s16x8 v = *(const s16x8*)&Ps[w][it2 * 16 + lr][jcq * 32 + lg * 8];
            size_t o = (((size_t)(itl_base + it2)) * 64 + jb * 4 + jcq) * 512 + l * 8;
            *(s16x8*)&Pg[o] = v;
        }
}

// ---------------- k_out: out = P @ MV^T; direct frag loads, distance-2 prefetch ----
// grid 512: b=bid&7; r=bid>>3: vb=r&3, ibb=r>>2 (4 it x 8 vt per block)
// 4 waves as 2(i) x 2(v); wave = 2 it-tiles x 4 vt-tiles (32 i x 64 v)
__global__ __launch_bounds__(256) void k_out(
    const unsigned short* __restrict__ P0, const unsigned short* __restrict__ MVf,
    float* __restrict__ out) {
    int bid = blockIdx.x;
    int b = bid & 7, r = bid >> 3;
    int vb = r & 3, ibb = r >> 2;
    int t = threadIdx.x, w = t >> 6, l = t & 63, lr = l & 15, lg = l >> 4;
    int wi = w >> 1, wv = w & 1;
    int it0 = ibb * 4 + wi * 2;
    const unsigned short* Pb = P0 + (size_t)b * PBF;
    const unsigned short* pA0 = Pb + ((size_t)it0 * 64) * 512 + l * 8;
    const unsigned short* pA1 = Pb + ((size_t)(it0 + 1) * 64) * 512 + l * 8;
    int vt0 = vb * 8 + wv * 4;
    const unsigned short* pB = MVf + (((size_t)b * 32 + vt0) * 64) * 512 + l * 8;

    f32x4 acc[2][4];
#pragma unroll
    for (int ii = 0; ii < 2; ++ii)
#pragma unroll
        for (int tv = 0; tv < 4; ++tv) acc[ii][tv] = (f32x4){0.f, 0.f, 0.f, 0.f};

    // distance-2 register pipeline: cur (jc), nxt (jc+1), tmp <- jc+2
    s16x8 ca0 = *(const s16x8*)&pA0[0];
    s16x8 ca1 = *(const s16x8*)&pA1[0];
    s16x8 cb[4];
#pragma unroll
    for (int tv = 0; tv < 4; ++tv) cb[tv] = *(const s16x8*)&pB[(size_t)tv * 64 * 512];
    s16x8 na0 = *(const s16x8*)&pA0[512];
    s16x8 na1 = *(const s16x8*)&pA1[512];
    s16x8 nb[4];
#pragma unroll
    for (int tv = 0; tv < 4; ++tv) nb[tv] = *(const s16x8*)&pB[(size_t)tv * 64 * 512 + 512];

#pragma unroll 1
    for (int jc = 0; jc < 64; ++jc) {
        s16x8 ta0, ta1, tb[4];
        if (jc < 62) {
            ta0 = *(const s16x8*)&pA0[(size_t)(jc + 2) * 512];
            ta1 = *(const s16x8*)&pA1[(size_t)(jc + 2) * 512];
#pragma unroll
            for (int tv = 0; tv < 4; ++tv)
                tb[tv] = *(const s16x8*)&pB[(size_t)tv * 64 * 512 + (size_t)(jc + 2) * 512];
        } else {
            ta0 = na0; ta1 = na1;
#pragma unroll
            for (int tv = 0; tv < 4; ++tv) tb[tv] = nb[tv];
        }
#pragma unroll
        for (int tv = 0; tv < 4; ++tv) {
            acc[0][tv] = __builtin_amdgcn_mfma_f32_16x16x32_bf16(ca0, cb[tv], acc[0][tv], 0, 0, 0);
            acc[1][tv] = __builtin_amdgcn_mfma_f32_16x16x32_bf16(ca1, cb[tv], acc[1][tv], 0, 0, 0);
        }
        ca0 = na0; ca1 = na1;
#pragma unroll
        for (int tv = 0; tv < 4; ++tv) cb[tv] = nb[tv];
        na0 = ta0; na1 = ta1;
#pragma unroll
        for (int tv = 0; tv < 4; ++tv) nb[tv] = tb[tv];
    }
    float* ob = out + (size_t)b * 1048576;
#pragma unroll
    for (int ii = 0; ii < 2; ++ii)
#pragma unroll
        for (int tv = 0; tv < 4; ++tv)
#pragma unroll
            for (int rr = 0; rr < 4; ++rr) {
                int i = (it0 + ii) * 16 + lg * 4 + rr;
                int v = (vt0 + tv) * 16 + lr;
                ob[(size_t)i * VD + v] = acc[ii][tv][rr];
            }
}

extern "C" void kernel_launch(void* const* d_in, const int* in_sizes, int n_in,
                              void* d_out, int out_size, void* d_ws, size_t ws_size,
                              hipStream_t stream) {
    const float* m_key   = (const float*)d_in[0];
    const float* m_val   = (const float*)d_in[1];
    const float* q_key   = (const float*)d_in[2];
    const float* q_val   = (const float*)d_in[3];
    const float* p_m_key = (const float*)d_in[4];
    const float* p_q_key = (const float*)d_in[5];
    float* out = (float*)d_out;
    char* ws = (char*)d_ws;
    if (ws_size < WS_NEED) return;

    unsigned short* KT = (unsigned short*)(ws + WS_KT);
    unsigned short* QB = (unsigned short*)(ws + WS_QB);
    unsigned short* MV = (unsigned short*)(ws + WS_MV);
    float* d_part = (float*)(ws + WS_D);
    unsigned short* P0 = (unsigned short*)(ws + WS_P);

    k_prep<<<2560, 256, 0, stream>>>(m_key, p_m_key, q_key, p_q_key, m_val, q_val,
                                     KT, QB, MV, out);
    k_stats<<<1024, 256, 0, stream>>>(KT, QB, d_part);
    k_pmat<<<1024, 256, 0, stream>>>(KT, QB, d_part, P0);
    k_out<<<512, 256, 0, stream>>>(P0, MV, out);
}

// Round 9
// 97.983 us; speedup vs baseline: 1.3370x; 1.3370x over previous
//
#include <hip/hip_runtime.h>
#include <hip/hip_bf16.h>

#define DEVI __device__ __forceinline__
#define AS1 __attribute__((address_space(1)))
#define AS3 __attribute__((address_space(3)))

typedef float f32x4 __attribute__((ext_vector_type(4)));
typedef _Float16 f16x8 __attribute__((ext_vector_type(8)));
typedef short s16x8 __attribute__((ext_vector_type(8)));

constexpr int NB = 8;     // batch
constexpr int HW = 1024;  // i (query) dim
constexpr int KD = 128;   // QK reduction dim
constexpr int VD = 512;   // value dim
constexpr int NJ = 2048;  // j (key/col) dim

// Fragment-major layouts: [..tile..][..k-chunk..][lane 64][elem 8]
// QB f16  [2 src][8 b][64 it][4 kc][512]
// KT f16  [2 src][8 b][128 jt][4 kc][512]
// MV bf16 [8 b][32 vt][64 jc][512]
// P  bf16 [8 b][64 it][64 kchunk][512]
constexpr size_t WS_KT = 0;                                    // 8.39 MB
constexpr size_t WS_QB = WS_KT + (size_t)2*NB*NJ*KD*2;         // 4.19 MB
constexpr size_t WS_MV = WS_QB + (size_t)2*NB*HW*KD*2;         // 16.78 MB
constexpr size_t WS_D  = WS_MV + (size_t)NB*VD*NJ*2;           // 2.10 MB
constexpr size_t WS_P  = WS_D  + (size_t)4*4*NB*NJ*4;          // 33.55 MB
constexpr size_t WS_NEED = WS_P + (size_t)NB*HW*NJ*2;          // ~65 MB total
constexpr size_t PBF = (size_t)64*64*512;                      // P shorts per batch

DEVI unsigned short f2bf(float x) {
    unsigned int u = __builtin_bit_cast(unsigned int, x);
    u += 0x7fffu + ((u >> 16) & 1u);
    return (unsigned short)(u >> 16);
}

// ---------------- k_prep: kt-transpose blocks + flat cvt/copy blocks ----------------
__global__ __launch_bounds__(256) void k_prep(
    const float* __restrict__ k0, const float* __restrict__ k1,
    const float* __restrict__ q0, const float* __restrict__ q1,
    const float* __restrict__ mv, const float* __restrict__ qv,
    unsigned short* __restrict__ KT, unsigned short* __restrict__ QB,
    unsigned short* __restrict__ MV, float* __restrict__ out) {
    __shared__ _Float16 Lt[64][136];
    int bid = blockIdx.x;
    int t = threadIdx.x;
    if (bid < 512) {
        int jt64 = bid & 31, b = (bid >> 5) & 7, src = bid >> 8;
        const float* K = (src ? k1 : k0) + (size_t)b * KD * NJ;
#pragma unroll
        for (int rd = 0; rd < 8; ++rd) {
            int task = t + rd * 256;
            int d = task >> 4, j4 = (task & 15) * 4;
            float4 v = *(const float4*)&K[(size_t)d * NJ + jt64 * 64 + j4];
            Lt[j4 + 0][d] = (_Float16)v.x;
            Lt[j4 + 1][d] = (_Float16)v.y;
            Lt[j4 + 2][d] = (_Float16)v.z;
            Lt[j4 + 3][d] = (_Float16)v.w;
        }
        __syncthreads();
        int w = t >> 6, l = t & 63, lr = l & 15, lg = l >> 4;
        int jt = jt64 * 4 + w;
#pragma unroll
        for (int kc = 0; kc < 4; ++kc) {
            f16x8 v = *(const f16x8*)&Lt[w * 16 + lr][kc * 32 + lg * 8];
            *(f16x8*)&KT[((((size_t)src * NB + b) * 128 + jt) * 4 + kc) * 512 + l * 8] = v;
        }
        return;
    }
    const int NTQ = 2 * NB * 64 * 4 * 64;        // 262144
    const int NTV = NB * 32 * 64 * 64;           // 1048576
    const int NQV = NB * VD * HW / 4;            // 1048576 float4 copies
    const int total = NTQ + NTV + NQV;
    const int stride = 2048 * 256;
    for (int task = (bid - 512) * 256 + t; task < total; task += stride) {
        if (task < NTQ) {
            int l = task & 63, kc = (task >> 6) & 3, it = (task >> 8) & 63;
            int b = (task >> 14) & 7, src = task >> 17;
            int lr = l & 15, lg = l >> 4;
            const float* q = (src ? q1 : q0) + (size_t)b * HW * KD
                           + (size_t)(it * 16 + lr) * KD + kc * 32 + lg * 8;
            float4 x0 = *(const float4*)q, x1 = *(const float4*)(q + 4);
            f16x8 r;
            r[0]=(_Float16)x0.x; r[1]=(_Float16)x0.y; r[2]=(_Float16)x0.z; r[3]=(_Float16)x0.w;
            r[4]=(_Float16)x1.x; r[5]=(_Float16)x1.y; r[6]=(_Float16)x1.z; r[7]=(_Float16)x1.w;
            *(f16x8*)&QB[((((size_t)src * NB + b) * 64 + it) * 4 + kc) * 512 + l * 8] = r;
        } else if (task < NTQ + NTV) {
            int t2 = task - NTQ;
            int l = t2 & 63, jc = (t2 >> 6) & 63, vt = (t2 >> 12) & 31, b = t2 >> 17;
            int lr = l & 15, lg = l >> 4;
            const float* p = mv + (size_t)b * VD * NJ + (size_t)(vt * 16 + lr) * NJ + jc * 32 + lg * 8;
            float4 x0 = *(const float4*)p, x1 = *(const float4*)(p + 4);
            s16x8 r;
            r[0]=(short)f2bf(x0.x); r[1]=(short)f2bf(x0.y); r[2]=(short)f2bf(x0.z); r[3]=(short)f2bf(x0.w);
            r[4]=(short)f2bf(x1.x); r[5]=(short)f2bf(x1.y); r[6]=(short)f2bf(x1.z); r[7]=(short)f2bf(x1.w);
            *(s16x8*)&MV[(((size_t)b * 32 + vt) * 64 + jc) * 512 + l * 8] = r;
        } else {
            int t3 = task - NTQ - NTV;
            int b = t3 >> 17, t4 = t3 & 131071;
            float4 v = ((const float4*)qv)[t3];
            ((float4*)(out + (size_t)b * 1048576 + 524288))[t4] = v;
        }
    }
}

// ---------------- k_stats: column sumexp; <=128 VGPR, 4 blocks/CU ----------------
__global__ __launch_bounds__(256, 4) void k_stats(
    const unsigned short* __restrict__ KTu, const unsigned short* __restrict__ QBu,
    float* __restrict__ d_part) {
    int bid = blockIdx.x;
    int b = bid & 7, r = bid >> 3;
    int jb = r & 15, is = (r >> 4) & 3, kc_s = r >> 6;
    int t = threadIdx.x, w = t >> 6, l = t & 63, lr = l & 15, lg = l >> 4;
    f16x8 bk[2][4];
#pragma unroll
    for (int tj = 0; tj < 2; ++tj) {
        int jt = jb * 8 + w * 2 + tj;
#pragma unroll
        for (int kst = 0; kst < 4; ++kst)
            bk[tj][kst] = *(const f16x8*)&KTu[((((size_t)kc_s * NB + b) * 128 + jt) * 4 + kst) * 512 + l * 8];
    }
    float dacc[2][2];
    dacc[0][0] = dacc[0][1] = dacc[1][0] = dacc[1][1] = 0.f;

#pragma unroll 2
    for (int it = 0; it < 16; ++it) {
        int itile = is * 16 + it;
#pragma unroll
        for (int qc = 0; qc < 2; ++qc) {
            f16x8 aq[4];
#pragma unroll
            for (int kst = 0; kst < 4; ++kst)
                aq[kst] = *(const f16x8*)&QBu[((((size_t)qc * NB + b) * 64 + itile) * 4 + kst) * 512 + l * 8];
#pragma unroll
            for (int tj = 0; tj < 2; ++tj) {
                f32x4 c = {0.f, 0.f, 0.f, 0.f};
#pragma unroll
                for (int kst = 0; kst < 4; ++kst)
                    c = __builtin_amdgcn_mfma_f32_16x16x32_f16(aq[kst], bk[tj][kst], c, 0, 0, 0);
#pragma unroll
                for (int rr = 0; rr < 4; ++rr) dacc[qc][tj] += __expf(c[rr]);
            }
        }
    }
#pragma unroll
    for (int qc = 0; qc < 2; ++qc)
#pragma unroll
        for (int tj = 0; tj < 2; ++tj) {
            float v = dacc[qc][tj];
            v += __shfl_xor(v, 16, 64);
            v += __shfl_xor(v, 32, 64);
            if (lg == 0) {
                int br = qc * 2 + kc_s;
                int j = (jb * 8 + w * 2 + tj) * 16 + lr;
                d_part[(((size_t)is * 4 + br) * NB + b) * NJ + j] = v;
            }
        }
}

// ---------------- k_pmat: 2-phase glds-staged bk + hoisted aq ----------------
// grid 1024: b=bid&7; r=bid>>3: jb=r&15, ib=r>>4 (0..7, 128 i per block); 4 waves
__global__ __launch_bounds__(256, 4) void k_pmat(
    const unsigned short* __restrict__ KTu, const unsigned short* __restrict__ QBu,
    const float* __restrict__ d_part, unsigned short* __restrict__ P0) {
    __shared__ _Float16 bkS[2][8][512];         // 16 KB dbuf: frag f = kc*4+kst
    __shared__ unsigned short Ps[4][32][36];    // 9.2 KB per-wave transpose strips
    __shared__ float ivd[4][128];               // 2 KB
    int bid = blockIdx.x;
    int b = bid & 7, r = bid >> 3;
    int jb = r & 15, ib = r >> 4;
    int t = threadIdx.x, w = t >> 6, l = t & 63, lr = l & 15, lg = l >> 4;

    for (int e = t; e < 512; e += 256) {
        int br = e >> 7, jj = e & 127;
        size_t o = ((size_t)br * NB + b) * NJ + jb * 128 + jj;
        const size_t S = (size_t)4 * NB * NJ;
        ivd[br][jj] = 1.0f / (d_part[o] + d_part[o + S] + d_part[o + 2 * S] + d_part[o + 3 * S]);
    }

    // hoisted A fragments: 16 frags = 64 VGPR, loaded once
    int itb0 = ib * 8 + w * 2;
    f16x8 aq[2][2][4];
#pragma unroll
    for (int qc = 0; qc < 2; ++qc)
#pragma unroll
        for (int ti = 0; ti < 2; ++ti)
#pragma unroll
            for (int kst = 0; kst < 4; ++kst)
                aq[qc][ti][kst] = *(const f16x8*)&QBu[((((size_t)qc * NB + b) * 64 + itb0 + ti) * 4 + kst) * 512 + l * 8];

    // stage jc=0 into buf 0: wave w stages frags 2w, 2w+1
    {
        int jt = jb * 8;
#pragma unroll
        for (int ff = 0; ff < 2; ++ff) {
            int f = w * 2 + ff, kc = f >> 2, kst = f & 3;
            const unsigned short* src = &KTu[((((size_t)kc * NB + b) * 128 + jt) * 4 + kst) * 512 + l * 8];
            __builtin_amdgcn_global_load_lds((const AS1 unsigned int*)src,
                                             (AS3 unsigned int*)&bkS[0][f][0], 16, 0, 0);
        }
    }
    __syncthreads();

#pragma unroll 1
    for (int jc = 0; jc < 8; ++jc) {
        int cur = jc & 1;
        if (jc < 7) {
            int jt = jb * 8 + jc + 1;
#pragma unroll
            for (int ff = 0; ff < 2; ++ff) {
                int f = w * 2 + ff, kc = f >> 2, kst = f & 3;
                const unsigned short* src = &KTu[((((size_t)kc * NB + b) * 128 + jt) * 4 + kst) * 512 + l * 8];
                __builtin_amdgcn_global_load_lds((const AS1 unsigned int*)src,
                                                 (AS3 unsigned int*)&bkS[cur ^ 1][f][0], 16, 0, 0);
            }
        }
        float iv[4];
#pragma unroll
        for (int br = 0; br < 4; ++br) iv[br] = ivd[br][jc * 16 + lr];
        f32x4 pacc[2] = {{0.f,0.f,0.f,0.f},{0.f,0.f,0.f,0.f}};
#pragma unroll
        for (int kc = 0; kc < 2; ++kc) {
            f16x8 bk[4];
#pragma unroll
            for (int kst = 0; kst < 4; ++kst)
                bk[kst] = *(const f16x8*)&bkS[cur][kc * 4 + kst][l * 8];
#pragma unroll
            for (int qc = 0; qc < 2; ++qc) {
                float ivb = iv[qc * 2 + kc];
#pragma unroll
                for (int ti = 0; ti < 2; ++ti) {
                    f32x4 c = {0.f, 0.f, 0.f, 0.f};
#pragma unroll
                    for (int kst = 0; kst < 4; ++kst)
                        c = __builtin_amdgcn_mfma_f32_16x16x32_f16(aq[qc][ti][kst], bk[kst], c, 0, 0, 0);
#pragma unroll
                    for (int rr = 0; rr < 4; ++rr)
                        pacc[ti][rr] += __expf(c[rr]) * ivb;
                }
            }
        }
        // write C-frag to wave-private strip (cols (jc&1)*16 + lr)
#pragma unroll
        for (int ti = 0; ti < 2; ++ti)
#pragma unroll
            for (int rr = 0; rr < 4; ++rr)
                Ps[w][ti * 16 + lg * 4 + rr][(jc & 1) * 16 + lr] = f2bf(pacc[ti][rr]);
        if (jc & 1) {
            // read back as A-frags for k-chunk jb*4 + (jc>>1); coalesced 16B stores
            unsigned short* Pg = P0 + (size_t)b * PBF;
            int kchunk = jb * 4 + (jc >> 1);
#pragma unroll
            for (int it2 = 0; it2 < 2; ++it2) {
                s16x8 v = *(const s16x8*)&Ps[w][it2 * 16 + lr][lg * 8];
                size_t o = (((size_t)(itb0 + it2)) * 64 + kchunk) * 512 + l * 8;
                *(s16x8*)&Pg[o] = v;
            }
        }
        __syncthreads();
    }
}

// ---------------- k_out: out = P @ MV^T; direct frag loads, distance-2 prefetch ----
__global__ __launch_bounds__(256) void k_out(
    const unsigned short* __restrict__ P0, const unsigned short* __restrict__ MVf,
    float* __restrict__ out) {
    int bid = blockIdx.x;
    int b = bid & 7, r = bid >> 3;
    int vb = r & 3, ibb = r >> 2;
    int t = threadIdx.x, w = t >> 6, l = t & 63, lr = l & 15, lg = l >> 4;
    int wi = w >> 1, wv = w & 1;
    int it0 = ibb * 4 + wi * 2;
    const unsigned short* Pb = P0 + (size_t)b * PBF;
    const unsigned short* pA0 = Pb + ((size_t)it0 * 64) * 512 + l * 8;
    const unsigned short* pA1 = Pb + ((size_t)(it0 + 1) * 64) * 512 + l * 8;
    int vt0 = vb * 8 + wv * 4;
    const unsigned short* pB = MVf + (((size_t)b * 32 + vt0) * 64) * 512 + l * 8;

    f32x4 acc[2][4];
#pragma unroll
    for (int ii = 0; ii < 2; ++ii)
#pragma unroll
        for (int tv = 0; tv < 4; ++tv) acc[ii][tv] = (f32x4){0.f, 0.f, 0.f, 0.f};

    s16x8 ca0 = *(const s16x8*)&pA0[0];
    s16x8 ca1 = *(const s16x8*)&pA1[0];
    s16x8 cb[4];
#pragma unroll
    for (int tv = 0; tv < 4; ++tv) cb[tv] = *(const s16x8*)&pB[(size_t)tv * 64 * 512];
    s16x8 na0 = *(const s16x8*)&pA0[512];
    s16x8 na1 = *(const s16x8*)&pA1[512];
    s16x8 nb[4];
#pragma unroll
    for (int tv = 0; tv < 4; ++tv) nb[tv] = *(const s16x8*)&pB[(size_t)tv * 64 * 512 + 512];

#pragma unroll 1
    for (int jc = 0; jc < 64; ++jc) {
        s16x8 ta0, ta1, tb[4];
        if (jc < 62) {
            ta0 = *(const s16x8*)&pA0[(size_t)(jc + 2) * 512];
            ta1 = *(const s16x8*)&pA1[(size_t)(jc + 2) * 512];
#pragma unroll
            for (int tv = 0; tv < 4; ++tv)
                tb[tv] = *(const s16x8*)&pB[(size_t)tv * 64 * 512 + (size_t)(jc + 2) * 512];
        } else {
            ta0 = na0; ta1 = na1;
#pragma unroll
            for (int tv = 0; tv < 4; ++tv) tb[tv] = nb[tv];
        }
#pragma unroll
        for (int tv = 0; tv < 4; ++tv) {
            acc[0][tv] = __builtin_amdgcn_mfma_f32_16x16x32_bf16(ca0, cb[tv], acc[0][tv], 0, 0, 0);
            acc[1][tv] = __builtin_amdgcn_mfma_f32_16x16x32_bf16(ca1, cb[tv], acc[1][tv], 0, 0, 0);
        }
        ca0 = na0; ca1 = na1;
#pragma unroll
        for (int tv = 0; tv < 4; ++tv) cb[tv] = nb[tv];
        na0 = ta0; na1 = ta1;
#pragma unroll
        for (int tv = 0; tv < 4; ++tv) nb[tv] = tb[tv];
    }
    float* ob = out + (size_t)b * 1048576;
#pragma unroll
    for (int ii = 0; ii < 2; ++ii)
#pragma unroll
        for (int tv = 0; tv < 4; ++tv)
#pragma unroll
            for (int rr = 0; rr < 4; ++rr) {
                int i = (it0 + ii) * 16 + lg * 4 + rr;
                int v = (vt0 + tv) * 16 + lr;
                ob[(size_t)i * VD + v] = acc[ii][tv][rr];
            }
}

extern "C" void kernel_launch(void* const* d_in, const int* in_sizes, int n_in,
                              void* d_out, int out_size, void* d_ws, size_t ws_size,
                              hipStream_t stream) {
    const float* m_key   = (const float*)d_in[0];
    const float* m_val   = (const float*)d_in[1];
    const float* q_key   = (const float*)d_in[2];
    const float* q_val   = (const float*)d_in[3];
    const float* p_m_key = (const float*)d_in[4];
    const float* p_q_key = (const float*)d_in[5];
    float* out = (float*)d_out;
    char* ws = (char*)d_ws;
    if (ws_size < WS_NEED) return;

    unsigned short* KT = (unsigned short*)(ws + WS_KT);
    unsigned short* QB = (unsigned short*)(ws + WS_QB);
    unsigned short* MV = (unsigned short*)(ws + WS_MV);
    float* d_part = (float*)(ws + WS_D);
    unsigned short* P0 = (unsigned short*)(ws + WS_P);

    k_prep<<<2560, 256, 0, stream>>>(m_key, p_m_key, q_key, p_q_key, m_val, q_val,
                                     KT, QB, MV, out);
    k_stats<<<1024, 256, 0, stream>>>(KT, QB, d_part);
    k_pmat<<<1024, 256, 0, stream>>>(KT, QB, d_part, P0);
    k_out<<<512, 256, 0, stream>>>(P0, MV, out);
}

// Round 10
// 93.484 us; speedup vs baseline: 1.4013x; 1.0481x over previous
//
#include <hip/hip_runtime.h>
#include <hip/hip_bf16.h>

#define DEVI __device__ __forceinline__
#define AS1 __attribute__((address_space(1)))
#define AS3 __attribute__((address_space(3)))

typedef float f32x4 __attribute__((ext_vector_type(4)));
typedef _Float16 f16x8 __attribute__((ext_vector_type(8)));
typedef short s16x8 __attribute__((ext_vector_type(8)));

constexpr int NB = 8;     // batch
constexpr int HW = 1024;  // i (query) dim
constexpr int KD = 128;   // QK reduction dim
constexpr int VD = 512;   // value dim
constexpr int NJ = 2048;  // j (key/col) dim
constexpr float LOG2E = 1.44269504088896f;

// Fragment-major layouts: [..tile..][..k-chunk..][lane 64][elem 8]
// QB f16  [2 src][8 b][64 it][4 kc][512]   (pre-scaled by log2(e))
// KT f16  [2 src][8 b][128 jt][4 kc][512]
// MV bf16 [8 b][32 vt][64 jc][512]
// P  bf16 [8 b][64 it][64 kchunk][512]
constexpr size_t WS_KT = 0;                                    // 8.39 MB
constexpr size_t WS_QB = WS_KT + (size_t)2*NB*NJ*KD*2;         // 4.19 MB
constexpr size_t WS_MV = WS_QB + (size_t)2*NB*HW*KD*2;         // 16.78 MB
constexpr size_t WS_D  = WS_MV + (size_t)NB*VD*NJ*2;           // 2.10 MB
constexpr size_t WS_P  = WS_D  + (size_t)4*4*NB*NJ*4;          // 33.55 MB
constexpr size_t WS_NEED = WS_P + (size_t)NB*HW*NJ*2;          // ~65 MB total
constexpr size_t PBF = (size_t)64*64*512;                      // P shorts per batch

DEVI unsigned short f2bf(float x) {
    unsigned int u = __builtin_bit_cast(unsigned int, x);
    u += 0x7fffu + ((u >> 16) & 1u);
    return (unsigned short)(u >> 16);
}

// ---------------- k_prep: kt-transpose blocks + flat cvt/copy blocks ----------------
__global__ __launch_bounds__(256) void k_prep(
    const float* __restrict__ k0, const float* __restrict__ k1,
    const float* __restrict__ q0, const float* __restrict__ q1,
    const float* __restrict__ mv, const float* __restrict__ qv,
    unsigned short* __restrict__ KT, unsigned short* __restrict__ QB,
    unsigned short* __restrict__ MV, float* __restrict__ out) {
    __shared__ _Float16 Lt[64][136];
    int bid = blockIdx.x;
    int t = threadIdx.x;
    if (bid < 512) {
        int jt64 = bid & 31, b = (bid >> 5) & 7, src = bid >> 8;
        const float* K = (src ? k1 : k0) + (size_t)b * KD * NJ;
#pragma unroll
        for (int rd = 0; rd < 8; ++rd) {
            int task = t + rd * 256;
            int d = task >> 4, j4 = (task & 15) * 4;
            float4 v = *(const float4*)&K[(size_t)d * NJ + jt64 * 64 + j4];
            Lt[j4 + 0][d] = (_Float16)v.x;
            Lt[j4 + 1][d] = (_Float16)v.y;
            Lt[j4 + 2][d] = (_Float16)v.z;
            Lt[j4 + 3][d] = (_Float16)v.w;
        }
        __syncthreads();
        int w = t >> 6, l = t & 63, lr = l & 15, lg = l >> 4;
        int jt = jt64 * 4 + w;
#pragma unroll
        for (int kc = 0; kc < 4; ++kc) {
            f16x8 v = *(const f16x8*)&Lt[w * 16 + lr][kc * 32 + lg * 8];
            *(f16x8*)&KT[((((size_t)src * NB + b) * 128 + jt) * 4 + kc) * 512 + l * 8] = v;
        }
        return;
    }
    const int NTQ = 2 * NB * 64 * 4 * 64;        // 262144
    const int NTV = NB * 32 * 64 * 64;           // 1048576
    const int NQV = NB * VD * HW / 4;            // 1048576 float4 copies
    const int total = NTQ + NTV + NQV;
    const int stride = 2048 * 256;
    for (int task = (bid - 512) * 256 + t; task < total; task += stride) {
        if (task < NTQ) {
            int l = task & 63, kc = (task >> 6) & 3, it = (task >> 8) & 63;
            int b = (task >> 14) & 7, src = task >> 17;
            int lr = l & 15, lg = l >> 4;
            const float* q = (src ? q1 : q0) + (size_t)b * HW * KD
                           + (size_t)(it * 16 + lr) * KD + kc * 32 + lg * 8;
            float4 x0 = *(const float4*)q, x1 = *(const float4*)(q + 4);
            f16x8 r;
            r[0]=(_Float16)(x0.x*LOG2E); r[1]=(_Float16)(x0.y*LOG2E);
            r[2]=(_Float16)(x0.z*LOG2E); r[3]=(_Float16)(x0.w*LOG2E);
            r[4]=(_Float16)(x1.x*LOG2E); r[5]=(_Float16)(x1.y*LOG2E);
            r[6]=(_Float16)(x1.z*LOG2E); r[7]=(_Float16)(x1.w*LOG2E);
            *(f16x8*)&QB[((((size_t)src * NB + b) * 64 + it) * 4 + kc) * 512 + l * 8] = r;
        } else if (task < NTQ + NTV) {
            int t2 = task - NTQ;
            int l = t2 & 63, jc = (t2 >> 6) & 63, vt = (t2 >> 12) & 31, b = t2 >> 17;
            int lr = l & 15, lg = l >> 4;
            const float* p = mv + (size_t)b * VD * NJ + (size_t)(vt * 16 + lr) * NJ + jc * 32 + lg * 8;
            float4 x0 = *(const float4*)p, x1 = *(const float4*)(p + 4);
            s16x8 r;
            r[0]=(short)f2bf(x0.x); r[1]=(short)f2bf(x0.y); r[2]=(short)f2bf(x0.z); r[3]=(short)f2bf(x0.w);
            r[4]=(short)f2bf(x1.x); r[5]=(short)f2bf(x1.y); r[6]=(short)f2bf(x1.z); r[7]=(short)f2bf(x1.w);
            *(s16x8*)&MV[(((size_t)b * 32 + vt) * 64 + jc) * 512 + l * 8] = r;
        } else {
            int t3 = task - NTQ - NTV;
            int b = t3 >> 17, t4 = t3 & 131071;
            float4 v = ((const float4*)qv)[t3];
            ((float4*)(out + (size_t)b * 1048576 + 524288))[t4] = v;
        }
    }
}

// ---------------- k_stats: column sum of exp2; <=128 VGPR, 4 blocks/CU ----------------
__global__ __launch_bounds__(256, 4) void k_stats(
    const unsigned short* __restrict__ KTu, const unsigned short* __restrict__ QBu,
    float* __restrict__ d_part) {
    int bid = blockIdx.x;
    int b = bid & 7, r = bid >> 3;
    int jb = r & 15, is = (r >> 4) & 3, kc_s = r >> 6;
    int t = threadIdx.x, w = t >> 6, l = t & 63, lr = l & 15, lg = l >> 4;
    f16x8 bk[2][4];
#pragma unroll
    for (int tj = 0; tj < 2; ++tj) {
        int jt = jb * 8 + w * 2 + tj;
#pragma unroll
        for (int kst = 0; kst < 4; ++kst)
            bk[tj][kst] = *(const f16x8*)&KTu[((((size_t)kc_s * NB + b) * 128 + jt) * 4 + kst) * 512 + l * 8];
    }
    float dacc[2][2];
    dacc[0][0] = dacc[0][1] = dacc[1][0] = dacc[1][1] = 0.f;

#pragma unroll 2
    for (int it = 0; it < 16; ++it) {
        int itile = is * 16 + it;
#pragma unroll
        for (int qc = 0; qc < 2; ++qc) {
            f16x8 aq[4];
#pragma unroll
            for (int kst = 0; kst < 4; ++kst)
                aq[kst] = *(const f16x8*)&QBu[((((size_t)qc * NB + b) * 64 + itile) * 4 + kst) * 512 + l * 8];
#pragma unroll
            for (int tj = 0; tj < 2; ++tj) {
                f32x4 c = {0.f, 0.f, 0.f, 0.f};
#pragma unroll
                for (int kst = 0; kst < 4; ++kst)
                    c = __builtin_amdgcn_mfma_f32_16x16x32_f16(aq[kst], bk[tj][kst], c, 0, 0, 0);
#pragma unroll
                for (int rr = 0; rr < 4; ++rr) dacc[qc][tj] += __builtin_amdgcn_exp2f(c[rr]);
            }
        }
    }
#pragma unroll
    for (int qc = 0; qc < 2; ++qc)
#pragma unroll
        for (int tj = 0; tj < 2; ++tj) {
            float v = dacc[qc][tj];
            v += __shfl_xor(v, 16, 64);
            v += __shfl_xor(v, 32, 64);
            if (lg == 0) {
                int br = qc * 2 + kc_s;
                int j = (jb * 8 + w * 2 + tj) * 16 + lr;
                d_part[(((size_t)is * 4 + br) * NB + b) * NJ + j] = v;
            }
        }
}

// ---------------- k_pmat: 2-phase glds-staged bk + hoisted aq ----------------
// grid 1024: b=bid&7; r=bid>>3: jb=r&15, ib=r>>4 (0..7, 128 i per block); 4 waves
__global__ __launch_bounds__(256, 4) void k_pmat(
    const unsigned short* __restrict__ KTu, const unsigned short* __restrict__ QBu,
    const float* __restrict__ d_part, unsigned short* __restrict__ P0) {
    __shared__ _Float16 bkS[2][8][512];         // 16 KB dbuf: frag f = kc*4+kst
    __shared__ unsigned short Ps[4][32][36];    // 9.2 KB per-wave transpose strips
    __shared__ float ivd[4][128];               // 2 KB
    int bid = blockIdx.x;
    int b = bid & 7, r = bid >> 3;
    int jb = r & 15, ib = r >> 4;
    int t = threadIdx.x, w = t >> 6, l = t & 63, lr = l & 15, lg = l >> 4;

    for (int e = t; e < 512; e += 256) {
        int br = e >> 7, jj = e & 127;
        size_t o = ((size_t)br * NB + b) * NJ + jb * 128 + jj;
        const size_t S = (size_t)4 * NB * NJ;
        ivd[br][jj] = 1.0f / (d_part[o] + d_part[o + S] + d_part[o + 2 * S] + d_part[o + 3 * S]);
    }

    // hoisted A fragments: 16 frags = 64 VGPR, loaded once
    int itb0 = ib * 8 + w * 2;
    f16x8 aq[2][2][4];
#pragma unroll
    for (int qc = 0; qc < 2; ++qc)
#pragma unroll
        for (int ti = 0; ti < 2; ++ti)
#pragma unroll
            for (int kst = 0; kst < 4; ++kst)
                aq[qc][ti][kst] = *(const f16x8*)&QBu[((((size_t)qc * NB + b) * 64 + itb0 + ti) * 4 + kst) * 512 + l * 8];

    // stage jc=0 into buf 0: wave w stages frags 2w, 2w+1
    {
        int jt = jb * 8;
#pragma unroll
        for (int ff = 0; ff < 2; ++ff) {
            int f = w * 2 + ff, kc = f >> 2, kst = f & 3;
            const unsigned short* src = &KTu[((((size_t)kc * NB + b) * 128 + jt) * 4 + kst) * 512 + l * 8];
            __builtin_amdgcn_global_load_lds((const AS1 unsigned int*)src,
                                             (AS3 unsigned int*)&bkS[0][f][0], 16, 0, 0);
        }
    }
    __syncthreads();

#pragma unroll 1
    for (int jc = 0; jc < 8; ++jc) {
        int cur = jc & 1;
        if (jc < 7) {
            int jt = jb * 8 + jc + 1;
#pragma unroll
            for (int ff = 0; ff < 2; ++ff) {
                int f = w * 2 + ff, kc = f >> 2, kst = f & 3;
                const unsigned short* src = &KTu[((((size_t)kc * NB + b) * 128 + jt) * 4 + kst) * 512 + l * 8];
                __builtin_amdgcn_global_load_lds((const AS1 unsigned int*)src,
                                                 (AS3 unsigned int*)&bkS[cur ^ 1][f][0], 16, 0, 0);
            }
        }
        float iv[4];
#pragma unroll
        for (int br = 0; br < 4; ++br) iv[br] = ivd[br][jc * 16 + lr];
        f32x4 pacc[2] = {{0.f,0.f,0.f,0.f},{0.f,0.f,0.f,0.f}};
#pragma unroll
        for (int kc = 0; kc < 2; ++kc) {
            f16x8 bk[4];
#pragma unroll
            for (int kst = 0; kst < 4; ++kst)
                bk[kst] = *(const f16x8*)&bkS[cur][kc * 4 + kst][l * 8];
#pragma unroll
            for (int qc = 0; qc < 2; ++qc) {
                float ivb = iv[qc * 2 + kc];
#pragma unroll
                for (int ti = 0; ti < 2; ++ti) {
                    f32x4 c = {0.f, 0.f, 0.f, 0.f};
#pragma unroll
                    for (int kst = 0; kst < 4; ++kst)
                        c = __builtin_amdgcn_mfma_f32_16x16x32_f16(aq[qc][ti][kst], bk[kst], c, 0, 0, 0);
#pragma unroll
                    for (int rr = 0; rr < 4; ++rr)
                        pacc[ti][rr] += __builtin_amdgcn_exp2f(c[rr]) * ivb;
                }
            }
        }
        // write C-frag to wave-private strip (cols (jc&1)*16 + lr)
#pragma unroll
        for (int ti = 0; ti < 2; ++ti)
#pragma unroll
            for (int rr = 0; rr < 4; ++rr)
                Ps[w][ti * 16 + lg * 4 + rr][(jc & 1) * 16 + lr] = f2bf(pacc[ti][rr]);
        if (jc & 1) {
            // read back as A-frags for k-chunk jb*4 + (jc>>1); coalesced 16B stores
            unsigned short* Pg = P0 + (size_t)b * PBF;
            int kchunk = jb * 4 + (jc >> 1);
#pragma unroll
            for (int it2 = 0; it2 < 2; ++it2) {
                s16x8 v = *(const s16x8*)&Ps[w][it2 * 16 + lr][lg * 8];
                size_t o = (((size_t)(itb0 + it2)) * 64 + kchunk) * 512 + l * 8;
                *(s16x8*)&Pg[o] = v;
            }
        }
        __syncthreads();
    }
}

// ---------------- k_out: out = P @ MV^T; glds-shared B tiles, 4-jc dbuf stages ------
// grid 512: b=bid&7; r=bid>>3: vb=r&3, ibb=r>>2; 4 waves; wave w: it=ibb*4+w, all 8 vt
__global__ __launch_bounds__(256) void k_out(
    const unsigned short* __restrict__ P0, const unsigned short* __restrict__ MVf,
    float* __restrict__ out) {
    __shared__ s16x8 Bs[2][4][8][64];   // 64 KB: [buf][jj][vt][lane]
    int bid = blockIdx.x;
    int b = bid & 7, r = bid >> 3;
    int vb = r & 3, ibb = r >> 2;
    int t = threadIdx.x, w = t >> 6, l = t & 63, lr = l & 15, lg = l >> 4;
    int it = ibb * 4 + w;
    const unsigned short* pA = P0 + (size_t)b * PBF + ((size_t)it * 64) * 512 + l * 8;
    const unsigned short* MB = MVf + (((size_t)b * 32 + vb * 8) * 64) * 512;

    f32x4 acc[8];
#pragma unroll
    for (int vt = 0; vt < 8; ++vt) acc[vt] = (f32x4){0.f, 0.f, 0.f, 0.f};

    // STAGE(buf, jc0): 32 frags (4 jc x 8 vt); wave w stages f = w*8..w*8+8
#define STAGE(buf, jc0)                                                              \
    {                                                                                \
        _Pragma("unroll")                                                            \
        for (int ff = 0; ff < 8; ++ff) {                                             \
            int f = w * 8 + ff, jj = f >> 3, vt = f & 7;                             \
            const unsigned short* src = MB + ((size_t)vt * 64 + (jc0) + jj) * 512 + l * 8; \
            __builtin_amdgcn_global_load_lds((const AS1 unsigned int*)src,           \
                                             (AS3 unsigned int*)&Bs[buf][jj][vt][0], 16, 0, 0); \
        }                                                                            \
    }

    STAGE(0, 0)
    s16x8 pc[4], pn[4];
#pragma unroll
    for (int jj = 0; jj < 4; ++jj) pc[jj] = *(const s16x8*)&pA[(size_t)jj * 512];
    __syncthreads();

#pragma unroll 1
    for (int p = 0; p < 16; ++p) {
        int cur = p & 1;
        if (p < 15) {
            STAGE(cur ^ 1, (p + 1) * 4)
#pragma unroll
            for (int jj = 0; jj < 4; ++jj)
                pn[jj] = *(const s16x8*)&pA[(size_t)((p + 1) * 4 + jj) * 512];
        }
#pragma unroll
        for (int jj = 0; jj < 4; ++jj)
#pragma unroll
            for (int vt = 0; vt < 8; ++vt)
                acc[vt] = __builtin_amdgcn_mfma_f32_16x16x32_bf16(pc[jj], Bs[cur][jj][vt][l], acc[vt], 0, 0, 0);
        __syncthreads();
#pragma unroll
        for (int jj = 0; jj < 4; ++jj) pc[jj] = pn[jj];
    }
#undef STAGE
    float* ob = out + (size_t)b * 1048576;
    int i0 = it * 16;
#pragma unroll
    for (int vt = 0; vt < 8; ++vt)
#pragma unroll
        for (int rr = 0; rr < 4; ++rr) {
            int i = i0 + lg * 4 + rr;
            int v = vb * 128 + vt * 16 + lr;
            ob[(size_t)i * VD + v] = acc[vt][rr];
        }
}

extern "C" void kernel_launch(void* const* d_in, const int* in_sizes, int n_in,
                              void* d_out, int out_size, void* d_ws, size_t ws_size,
                              hipStream_t stream) {
    const float* m_key   = (const float*)d_in[0];
    const float* m_val   = (const float*)d_in[1];
    const float* q_key   = (const float*)d_in[2];
    const float* q_val   = (const float*)d_in[3];
    const float* p_m_key = (const float*)d_in[4];
    const float* p_q_key = (const float*)d_in[5];
    float* out = (float*)d_out;
    char* ws = (char*)d_ws;
    if (ws_size < WS_NEED) return;

    unsigned short* KT = (unsigned short*)(ws + WS_KT);
    unsigned short* QB = (unsigned short*)(ws + WS_QB);
    unsigned short* MV = (unsigned short*)(ws + WS_MV);
    float* d_part = (float*)(ws + WS_D);
    unsigned short* P0 = (unsigned short*)(ws + WS_P);

    k_prep<<<2560, 256, 0, stream>>>(m_key, p_m_key, q_key, p_q_key, m_val, q_val,
                                     KT, QB, MV, out);
    k_stats<<<1024, 256, 0, stream>>>(KT, QB, d_part);
    k_pmat<<<1024, 256, 0, stream>>>(KT, QB, d_part, P0);
    k_out<<<512, 256, 0, stream>>>(P0, MV, out);
}

// Round 11
// 92.143 us; speedup vs baseline: 1.4217x; 1.0146x over previous
//
#include <hip/hip_runtime.h>
#include <hip/hip_bf16.h>

#define DEVI __device__ __forceinline__
#define AS1 __attribute__((address_space(1)))
#define AS3 __attribute__((address_space(3)))

typedef float f32x4 __attribute__((ext_vector_type(4)));
typedef _Float16 f16x8 __attribute__((ext_vector_type(8)));
typedef short s16x8 __attribute__((ext_vector_type(8)));

constexpr int NB = 8;     // batch
constexpr int HW = 1024;  // i (query) dim
constexpr int KD = 128;   // QK reduction dim
constexpr int VD = 512;   // value dim
constexpr int NJ = 2048;  // j (key/col) dim
constexpr float LOG2E = 1.44269504088896f;

// Fragment-major layouts: [..tile..][..k-chunk..][lane 64][elem 8]
// QB f16  [2 src][8 b][64 it][4 kc][512]   (pre-scaled by log2(e))
// KT f16  [2 src][8 b][128 jt][4 kc][512]
// MV bf16 [8 b][32 vt][64 jc][512]
// P  bf16 [8 b][64 it][64 kchunk][512]
constexpr size_t WS_KT = 0;                                    // 8.39 MB
constexpr size_t WS_QB = WS_KT + (size_t)2*NB*NJ*KD*2;         // 4.19 MB
constexpr size_t WS_MV = WS_QB + (size_t)2*NB*HW*KD*2;         // 16.78 MB
constexpr size_t WS_D  = WS_MV + (size_t)NB*VD*NJ*2;           // 2.10 MB
constexpr size_t WS_P  = WS_D  + (size_t)4*4*NB*NJ*4;          // 33.55 MB
constexpr size_t WS_NEED = WS_P + (size_t)NB*HW*NJ*2;          // ~65 MB total
constexpr size_t PBF = (size_t)64*64*512;                      // P shorts per batch

DEVI unsigned short f2bf(float x) {
    unsigned int u = __builtin_bit_cast(unsigned int, x);
    u += 0x7fffu + ((u >> 16) & 1u);
    return (unsigned short)(u >> 16);
}

// ---------------- k_prep: 4 sections, all streams coalesced ----------------
// [0,512):      KT transpose (LDS tile)
// [512,1536):   MV cvt via LDS tile  (b, vt, jq)
// [1536,1664):  QB cvt via LDS tile  (src, b, itq), folds LOG2E
// [1664,2048):  qval float4 grid-stride copy
__global__ __launch_bounds__(256) void k_prep(
    const float* __restrict__ k0, const float* __restrict__ k1,
    const float* __restrict__ q0, const float* __restrict__ q1,
    const float* __restrict__ mv, const float* __restrict__ qv,
    unsigned short* __restrict__ KT, unsigned short* __restrict__ QB,
    unsigned short* __restrict__ MV, float* __restrict__ out) {
    __shared__ _Float16 Lt[128][138];   // 35.3 KB, shared by all sections
    int bid = blockIdx.x;
    int t = threadIdx.x;
    int w = t >> 6, l = t & 63, lr = l & 15, lg = l >> 4;

    if (bid < 512) {
        // ---- KT transpose: tile [128 d][64 j] ----
        _Float16(*Lk)[136] = (_Float16(*)[136])&Lt[0][0];
        int jt64 = bid & 31, b = (bid >> 5) & 7, src = bid >> 8;
        const float* K = (src ? k1 : k0) + (size_t)b * KD * NJ;
#pragma unroll
        for (int rd = 0; rd < 8; ++rd) {
            int task = t + rd * 256;
            int d = task >> 4, j4 = (task & 15) * 4;
            float4 v = *(const float4*)&K[(size_t)d * NJ + jt64 * 64 + j4];
            Lk[j4 + 0][d] = (_Float16)v.x;
            Lk[j4 + 1][d] = (_Float16)v.y;
            Lk[j4 + 2][d] = (_Float16)v.z;
            Lk[j4 + 3][d] = (_Float16)v.w;
        }
        __syncthreads();
        int jt = jt64 * 4 + w;
#pragma unroll
        for (int kc = 0; kc < 4; ++kc) {
            f16x8 v = *(const f16x8*)&Lk[w * 16 + lr][kc * 32 + lg * 8];
            *(f16x8*)&KT[((((size_t)src * NB + b) * 128 + jt) * 4 + kc) * 512 + l * 8] = v;
        }
        return;
    }
    if (bid < 1536) {
        // ---- MV cvt: tile 16 v x 512 j, coalesced rows -> frags ----
        unsigned short(*Lv)[522] = (unsigned short(*)[522])&Lt[0][0];  // 16.7 KB
        int bid2 = bid - 512;
        int jq = bid2 & 3, vt = (bid2 >> 2) & 31, b = bid2 >> 7;
        const float* src = mv + (size_t)b * VD * NJ + (size_t)(vt * 16) * NJ + jq * 512;
#pragma unroll
        for (int rd = 0; rd < 8; ++rd) {
            int idx = rd * 256 + t;          // 2048 float4 tasks
            int row = idx >> 7, c4 = (idx & 127) * 4;
            float4 v = *(const float4*)&src[(size_t)row * NJ + c4];
            Lv[row][c4 + 0] = f2bf(v.x);
            Lv[row][c4 + 1] = f2bf(v.y);
            Lv[row][c4 + 2] = f2bf(v.z);
            Lv[row][c4 + 3] = f2bf(v.w);
        }
        __syncthreads();
#pragma unroll
        for (int rd = 0; rd < 4; ++rd) {
            int f = rd * 4 + w;              // local jc 0..15
            s16x8 v = *(const s16x8*)&Lv[lr][f * 32 + lg * 8];
            *(s16x8*)&MV[(((size_t)b * 32 + vt) * 64 + jq * 16 + f) * 512 + l * 8] = v;
        }
        return;
    }
    if (bid < 1664) {
        // ---- QB cvt: tile 128 i x 128 d, coalesced rows -> frags, xLOG2E ----
        int bid3 = bid - 1536;
        int itq = bid3 & 7, b = (bid3 >> 3) & 7, src_q = bid3 >> 6;
        const float* q = (src_q ? q1 : q0) + (size_t)(b * HW + itq * 128) * KD;
#pragma unroll
        for (int rd = 0; rd < 16; ++rd) {
            int idx = rd * 256 + t;          // 4096 float4 tasks
            int row = idx >> 5, c4 = (idx & 31) * 4;
            float4 v = *(const float4*)&q[(size_t)row * KD + c4];
            Lt[row][c4 + 0] = (_Float16)(v.x * LOG2E);
            Lt[row][c4 + 1] = (_Float16)(v.y * LOG2E);
            Lt[row][c4 + 2] = (_Float16)(v.z * LOG2E);
            Lt[row][c4 + 3] = (_Float16)(v.w * LOG2E);
        }
        __syncthreads();
#pragma unroll
        for (int rd = 0; rd < 8; ++rd) {
            int f = rd * 4 + w;              // 32 frags: it_l = f>>2, kc = f&3
            int it_l = f >> 2, kc = f & 3;
            f16x8 v = *(const f16x8*)&Lt[it_l * 16 + lr][kc * 32 + lg * 8];
            *(f16x8*)&QB[((((size_t)src_q * NB + b) * 64 + itq * 8 + it_l) * 4 + kc) * 512 + l * 8] = v;
        }
        return;
    }
    // ---- qval copy ----
    const int NQV = NB * VD * HW / 4;        // 1048576 float4
    for (int t3 = (bid - 1664) * 256 + t; t3 < NQV; t3 += 384 * 256) {
        int b = t3 >> 17, t4 = t3 & 131071;
        float4 v = ((const float4*)qv)[t3];
        ((float4*)(out + (size_t)b * 1048576 + 524288))[t4] = v;
    }
}

// ---------------- k_stats: column sum of exp2; <=128 VGPR, 4 blocks/CU ----------------
__global__ __launch_bounds__(256, 4) void k_stats(
    const unsigned short* __restrict__ KTu, const unsigned short* __restrict__ QBu,
    float* __restrict__ d_part) {
    int bid = blockIdx.x;
    int b = bid & 7, r = bid >> 3;
    int jb = r & 15, is = (r >> 4) & 3, kc_s = r >> 6;
    int t = threadIdx.x, w = t >> 6, l = t & 63, lr = l & 15, lg = l >> 4;
    f16x8 bk[2][4];
#pragma unroll
    for (int tj = 0; tj < 2; ++tj) {
        int jt = jb * 8 + w * 2 + tj;
#pragma unroll
        for (int kst = 0; kst < 4; ++kst)
            bk[tj][kst] = *(const f16x8*)&KTu[((((size_t)kc_s * NB + b) * 128 + jt) * 4 + kst) * 512 + l * 8];
    }
    float dacc[2][2];
    dacc[0][0] = dacc[0][1] = dacc[1][0] = dacc[1][1] = 0.f;

#pragma unroll 2
    for (int it = 0; it < 16; ++it) {
        int itile = is * 16 + it;
#pragma unroll
        for (int qc = 0; qc < 2; ++qc) {
            f16x8 aq[4];
#pragma unroll
            for (int kst = 0; kst < 4; ++kst)
                aq[kst] = *(const f16x8*)&QBu[((((size_t)qc * NB + b) * 64 + itile) * 4 + kst) * 512 + l * 8];
#pragma unroll
            for (int tj = 0; tj < 2; ++tj) {
                f32x4 c = {0.f, 0.f, 0.f, 0.f};
#pragma unroll
                for (int kst = 0; kst < 4; ++kst)
                    c = __builtin_amdgcn_mfma_f32_16x16x32_f16(aq[kst], bk[tj][kst], c, 0, 0, 0);
#pragma unroll
                for (int rr = 0; rr < 4; ++rr) dacc[qc][tj] += __builtin_amdgcn_exp2f(c[rr]);
            }
        }
    }
#pragma unroll
    for (int qc = 0; qc < 2; ++qc)
#pragma unroll
        for (int tj = 0; tj < 2; ++tj) {
            float v = dacc[qc][tj];
            v += __shfl_xor(v, 16, 64);
            v += __shfl_xor(v, 32, 64);
            if (lg == 0) {
                int br = qc * 2 + kc_s;
                int j = (jb * 8 + w * 2 + tj) * 16 + lr;
                d_part[(((size_t)is * 4 + br) * NB + b) * NJ + j] = v;
            }
        }
}

// ---------------- k_pmat: 2-phase glds-staged bk + hoisted aq ----------------
// grid 1024: b=bid&7; r=bid>>3: jb=r&15, ib=r>>4 (0..7, 128 i per block); 4 waves
__global__ __launch_bounds__(256, 4) void k_pmat(
    const unsigned short* __restrict__ KTu, const unsigned short* __restrict__ QBu,
    const float* __restrict__ d_part, unsigned short* __restrict__ P0) {
    __shared__ _Float16 bkS[2][8][512];         // 16 KB dbuf: frag f = kc*4+kst
    __shared__ unsigned short Ps[4][32][36];    // 9.2 KB per-wave transpose strips
    __shared__ float ivd[4][128];               // 2 KB
    int bid = blockIdx.x;
    int b = bid & 7, r = bid >> 3;
    int jb = r & 15, ib = r >> 4;
    int t = threadIdx.x, w = t >> 6, l = t & 63, lr = l & 15, lg = l >> 4;

    for (int e = t; e < 512; e += 256) {
        int br = e >> 7, jj = e & 127;
        size_t o = ((size_t)br * NB + b) * NJ + jb * 128 + jj;
        const size_t S = (size_t)4 * NB * NJ;
        ivd[br][jj] = 1.0f / (d_part[o] + d_part[o + S] + d_part[o + 2 * S] + d_part[o + 3 * S]);
    }

    // hoisted A fragments: 16 frags = 64 VGPR, loaded once
    int itb0 = ib * 8 + w * 2;
    f16x8 aq[2][2][4];
#pragma unroll
    for (int qc = 0; qc < 2; ++qc)
#pragma unroll
        for (int ti = 0; ti < 2; ++ti)
#pragma unroll
            for (int kst = 0; kst < 4; ++kst)
                aq[qc][ti][kst] = *(const f16x8*)&QBu[((((size_t)qc * NB + b) * 64 + itb0 + ti) * 4 + kst) * 512 + l * 8];

    // stage jc=0 into buf 0: wave w stages frags 2w, 2w+1
    {
        int jt = jb * 8;
#pragma unroll
        for (int ff = 0; ff < 2; ++ff) {
            int f = w * 2 + ff, kc = f >> 2, kst = f & 3;
            const unsigned short* src = &KTu[((((size_t)kc * NB + b) * 128 + jt) * 4 + kst) * 512 + l * 8];
            __builtin_amdgcn_global_load_lds((const AS1 unsigned int*)src,
                                             (AS3 unsigned int*)&bkS[0][f][0], 16, 0, 0);
        }
    }
    __syncthreads();

#pragma unroll 1
    for (int jc = 0; jc < 8; ++jc) {
        int cur = jc & 1;
        if (jc < 7) {
            int jt = jb * 8 + jc + 1;
#pragma unroll
            for (int ff = 0; ff < 2; ++ff) {
                int f = w * 2 + ff, kc = f >> 2, kst = f & 3;
                const unsigned short* src = &KTu[((((size_t)kc * NB + b) * 128 + jt) * 4 + kst) * 512 + l * 8];
                __builtin_amdgcn_global_load_lds((const AS1 unsigned int*)src,
                                                 (AS3 unsigned int*)&bkS[cur ^ 1][f][0], 16, 0, 0);
            }
        }
        float iv[4];
#pragma unroll
        for (int br = 0; br < 4; ++br) iv[br] = ivd[br][jc * 16 + lr];
        f32x4 pacc[2] = {{0.f,0.f,0.f,0.f},{0.f,0.f,0.f,0.f}};
#pragma unroll
        for (int kc = 0; kc < 2; ++kc) {
            f16x8 bk[4];
#pragma unroll
            for (int kst = 0; kst < 4; ++kst)
                bk[kst] = *(const f16x8*)&bkS[cur][kc * 4 + kst][l * 8];
#pragma unroll
            for (int qc = 0; qc < 2; ++qc) {
                float ivb = iv[qc * 2 + kc];
#pragma unroll
                for (int ti = 0; ti < 2; ++ti) {
                    f32x4 c = {0.f, 0.f, 0.f, 0.f};
#pragma unroll
                    for (int kst = 0; kst < 4; ++kst)
                        c = __builtin_amdgcn_mfma_f32_16x16x32_f16(aq[qc][ti][kst], bk[kst], c, 0, 0, 0);
#pragma unroll
                    for (int rr = 0; rr < 4; ++rr)
                        pacc[ti][rr] += __builtin_amdgcn_exp2f(c[rr]) * ivb;
                }
            }
        }
        // write C-frag to wave-private strip (cols (jc&1)*16 + lr)
#pragma unroll
        for (int ti = 0; ti < 2; ++ti)
#pragma unroll
            for (int rr = 0; rr < 4; ++rr)
                Ps[w][ti * 16 + lg * 4 + rr][(jc & 1) * 16 + lr] = f2bf(pacc[ti][rr]);
        if (jc & 1) {
            // read back as A-frags for k-chunk jb*4 + (jc>>1); coalesced 16B stores
            unsigned short* Pg = P0 + (size_t)b * PBF;
            int kchunk = jb * 4 + (jc >> 1);
#pragma unroll
            for (int it2 = 0; it2 < 2; ++it2) {
                s16x8 v = *(const s16x8*)&Ps[w][it2 * 16 + lr][lg * 8];
                size_t o = (((size_t)(itb0 + it2)) * 64 + kchunk) * 512 + l * 8;
                *(s16x8*)&Pg[o] = v;
            }
        }
        __syncthreads();
    }
}

// ---------------- k_out: out = P @ MV^T; glds-shared B tiles, 4-jc dbuf stages ------
// grid 512: b=bid&7; r=bid>>3: vb=r&3, ibb=r>>2; 4 waves; wave w: it=ibb*4+w, all 8 vt
__global__ __launch_bounds__(256) void k_out(
    const unsigned short* __restrict__ P0, const unsigned short* __restrict__ MVf,
    float* __restrict__ out) {
    __shared__ s16x8 Bs[2][4][8][64];   // 64 KB: [buf][jj][vt][lane]
    int bid = blockIdx.x;
    int b = bid & 7, r = bid >> 3;
    int vb = r & 3, ibb = r >> 2;
    int t = threadIdx.x, w = t >> 6, l = t & 63, lr = l & 15, lg = l >> 4;
    int it = ibb * 4 + w;
    const unsigned short* pA = P0 + (size_t)b * PBF + ((size_t)it * 64) * 512 + l * 8;
    const unsigned short* MB = MVf + (((size_t)b * 32 + vb * 8) * 64) * 512;

    f32x4 acc[8];
#pragma unroll
    for (int vt = 0; vt < 8; ++vt) acc[vt] = (f32x4){0.f, 0.f, 0.f, 0.f};

#define STAGE(buf, jc0)                                                              \
    {                                                                                \
        _Pragma("unroll")                                                            \
        for (int ff = 0; ff < 8; ++ff) {                                             \
            int f = w * 8 + ff, jj = f >> 3, vt = f & 7;                             \
            const unsigned short* src = MB + ((size_t)vt * 64 + (jc0) + jj) * 512 + l * 8; \
            __builtin_amdgcn_global_load_lds((const AS1 unsigned int*)src,           \
                                             (AS3 unsigned int*)&Bs[buf][jj][vt][0], 16, 0, 0); \
        }                                                                            \
    }

    STAGE(0, 0)
    s16x8 pc[4], pn[4];
#pragma unroll
    for (int jj = 0; jj < 4; ++jj) pc[jj] = *(const s16x8*)&pA[(size_t)jj * 512];
    __syncthreads();

#pragma unroll 1
    for (int p = 0; p < 16; ++p) {
        int cur = p & 1;
        if (p < 15) {
            STAGE(cur ^ 1, (p + 1) * 4)
#pragma unroll
            for (int jj = 0; jj < 4; ++jj)
                pn[jj] = *(const s16x8*)&pA[(size_t)((p + 1) * 4 + jj) * 512];
        }
#pragma unroll
        for (int jj = 0; jj < 4; ++jj)
#pragma unroll
            for (int vt = 0; vt < 8; ++vt)
                acc[vt] = __builtin_amdgcn_mfma_f32_16x16x32_bf16(pc[jj], Bs[cur][jj][vt][l], acc[vt], 0, 0, 0);
        __syncthreads();
#pragma unroll
        for (int jj = 0; jj < 4; ++jj) pc[jj] = pn[jj];
    }
#undef STAGE
    float* ob = out + (size_t)b * 1048576;
    int i0 = it * 16;
#pragma unroll
    for (int vt = 0; vt < 8; ++vt)
#pragma unroll
        for (int rr = 0; rr < 4; ++rr) {
            int i = i0 + lg * 4 + rr;
            int v = vb * 128 + vt * 16 + lr;
            ob[(size_t)i * VD + v] = acc[vt][rr];
        }
}

extern "C" void kernel_launch(void* const* d_in, const int* in_sizes, int n_in,
                              void* d_out, int out_size, void* d_ws, size_t ws_size,
                              hipStream_t stream) {
    const float* m_key   = (const float*)d_in[0];
    const float* m_val   = (const float*)d_in[1];
    const float* q_key   = (const float*)d_in[2];
    const float* q_val   = (const float*)d_in[3];
    const float* p_m_key = (const float*)d_in[4];
    const float* p_q_key = (const float*)d_in[5];
    float* out = (float*)d_out;
    char* ws = (char*)d_ws;
    if (ws_size < WS_NEED) return;

    unsigned short* KT = (unsigned short*)(ws + WS_KT);
    unsigned short* QB = (unsigned short*)(ws + WS_QB);
    unsigned short* MV = (unsigned short*)(ws + WS_MV);
    float* d_part = (float*)(ws + WS_D);
    unsigned short* P0 = (unsigned short*)(ws + WS_P);

    k_prep<<<2048, 256, 0, stream>>>(m_key, p_m_key, q_key, p_q_key, m_val, q_val,
                                     KT, QB, MV, out);
    k_stats<<<1024, 256, 0, stream>>>(KT, QB, d_part);
    k_pmat<<<1024, 256, 0, stream>>>(KT, QB, d_part, P0);
    k_out<<<512, 256, 0, stream>>>(P0, MV, out);
}